// Round 1
// baseline (6881.605 us; speedup 1.0000x reference)
//
#include <hip/hip_runtime.h>
#include <hip/hip_bf16.h>

// MultiHeadSelfAttention on MI355X (gfx950)
// Pipeline: [f32->bf16 x] [transpose W* -> bf16 N-major] -> 3x MFMA GEMM (QKV,
// scattered to (B,H,S,Dk), Q pre-scaled by 1/8) -> fp32 flash attention ->
// MFMA GEMM out-proj (fp32 out + bias).

#define D_MODEL 1024
#define NHEADS  16
#define DK      64
#define BATCH   4
#define SEQ     2048
#define MROWS   (BATCH*SEQ)   // 8192

typedef short bvec8 __attribute__((ext_vector_type(8)));   // 8 bf16 = 4 VGPRs (MFMA A/B frag)
typedef float fvec4 __attribute__((ext_vector_type(4)));   // MFMA C/D frag

__device__ __forceinline__ unsigned short f2bf(float f) {
    unsigned int x = __float_as_uint(f);
    x += 0x7fffu + ((x >> 16) & 1u);   // RNE
    return (unsigned short)(x >> 16);
}
__device__ __forceinline__ float bf2f(unsigned short u) {
    return __uint_as_float(((unsigned int)u) << 16);
}

// ---------------- prep kernels ----------------

__global__ void f32_to_bf16_k(const float* __restrict__ in,
                              unsigned short* __restrict__ out, int n4) {
    int i = blockIdx.x * 256 + threadIdx.x;
    if (i < n4) {
        float4 v = ((const float4*)in)[i];
        ushort4 o;
        o.x = f2bf(v.x); o.y = f2bf(v.y); o.z = f2bf(v.z); o.w = f2bf(v.w);
        ((ushort4*)out)[i] = o;
    }
}

// Wt[n][k] = (bf16) W[k][n]   (1024x1024)
__global__ void transpose_to_bf16_k(const float* __restrict__ W,
                                    unsigned short* __restrict__ Wt) {
    __shared__ float tile[32][33];
    int n0 = blockIdx.x * 32, k0 = blockIdx.y * 32;
    int tx = threadIdx.x & 31;
    int ty = (threadIdx.x >> 5) * 4;
#pragma unroll
    for (int i = 0; i < 4; ++i)
        tile[ty + i][tx] = W[(k0 + ty + i) * D_MODEL + n0 + tx];
    __syncthreads();
#pragma unroll
    for (int i = 0; i < 4; ++i)
        Wt[(n0 + ty + i) * D_MODEL + k0 + tx] = f2bf(tile[tx][ty + i]);
}

// ---------------- bf16 MFMA GEMM ----------------
// C(128x128/block) = A(M x 1024, bf16 row-major) * Bt^T (Bt is N x K bf16) + bias
// mode 0: store bf16 scattered to (b,h,s,d) with pre-store scale
// mode 1: store fp32 row-major (d_out)
__global__ __launch_bounds__(256, 2)
void gemm_bf16(const unsigned short* __restrict__ A,
               const unsigned short* __restrict__ Bt,
               const float* __restrict__ bias,
               void* __restrict__ Out, float scale, int mode) {
    __shared__ unsigned short As[128][72];   // +8 bf16 pad, 16B-aligned rows
    __shared__ unsigned short Bs[128][72];

    const int tid  = threadIdx.x;
    const int lane = tid & 63;
    const int w    = tid >> 6;
    const int wr   = w >> 1, wc = w & 1;     // 2x2 waves, 64x64 each
    const int quad = lane >> 4, l16 = lane & 15;
    const int rowBlock = blockIdx.y * 128;
    const int colBlock = blockIdx.x * 128;

    fvec4 acc[4][4] = {};

    for (int k0 = 0; k0 < D_MODEL; k0 += 64) {
#pragma unroll
        for (int it = 0; it < 4; ++it) {
            int c  = tid + it * 256;          // 1024 chunks of 8 bf16
            int r  = c >> 3;
            int cc = (c & 7) << 3;
            *(bvec8*)&As[r][cc] = *(const bvec8*)&A[(rowBlock + r) * D_MODEL + k0 + cc];
            *(bvec8*)&Bs[r][cc] = *(const bvec8*)&Bt[(colBlock + r) * D_MODEL + k0 + cc];
        }
        __syncthreads();
#pragma unroll
        for (int kk = 0; kk < 64; kk += 32) {
            bvec8 af[4], bfr[4];
#pragma unroll
            for (int i = 0; i < 4; ++i)
                af[i] = *(const bvec8*)&As[wr * 64 + i * 16 + l16][kk + quad * 8];
#pragma unroll
            for (int j = 0; j < 4; ++j)
                bfr[j] = *(const bvec8*)&Bs[wc * 64 + j * 16 + l16][kk + quad * 8];
#pragma unroll
            for (int i = 0; i < 4; ++i)
#pragma unroll
                for (int j = 0; j < 4; ++j)
                    acc[i][j] = __builtin_amdgcn_mfma_f32_16x16x32_bf16(
                        af[i], bfr[j], acc[i][j], 0, 0, 0);
        }
        __syncthreads();
    }

    // epilogue: D[row=quad*4+r][col=l16] per 16x16 tile (m89-verified mapping)
    if (mode == 0) {
        unsigned short* Oq = (unsigned short*)Out;
#pragma unroll
        for (int i = 0; i < 4; ++i) {
#pragma unroll
            for (int j = 0; j < 4; ++j) {
                int ncol = colBlock + wc * 64 + j * 16 + l16;
                float bv = bias[ncol];
                int h = ncol >> 6, d = ncol & 63;
#pragma unroll
                for (int r = 0; r < 4; ++r) {
                    int mrow = rowBlock + wr * 64 + i * 16 + quad * 4 + r;
                    int b = mrow >> 11, s = mrow & (SEQ - 1);
                    float v = (acc[i][j][r] + bv) * scale;
                    Oq[(((b * NHEADS + h) * SEQ + s) * DK) + d] = f2bf(v);
                }
            }
        }
    } else {
        float* Of = (float*)Out;
#pragma unroll
        for (int i = 0; i < 4; ++i) {
#pragma unroll
            for (int j = 0; j < 4; ++j) {
                int ncol = colBlock + wc * 64 + j * 16 + l16;
                float bv = bias[ncol];
#pragma unroll
                for (int r = 0; r < 4; ++r) {
                    int mrow = rowBlock + wr * 64 + i * 16 + quad * 4 + r;
                    Of[mrow * D_MODEL + ncol] = acc[i][j][r] + bv;
                }
            }
        }
    }
}

// ---------------- fp32 flash attention ----------------
// grid (32,16,4): one block per (q-tile of 64, head, batch). 256 thr = 16x16.
// thread (tx,ty): q rows ty*4..+3, d cols tx*4..+3. Online softmax in regs
// (all 16 tx threads hold identical m/l per row via shfl reductions).
__global__ __launch_bounds__(256, 2)
void attn_fp32(const unsigned short* __restrict__ Q,   // (B,H,S,Dk) bf16, pre-scaled 1/8
               const unsigned short* __restrict__ K,
               const unsigned short* __restrict__ V,
               unsigned short* __restrict__ O) {       // (B,S,H*Dk) bf16
    __shared__ __align__(16) unsigned short Qsh[64][72];  // bf16 Q tile (LDS budget)
    __shared__ __align__(16) float Ks[64 * 64];           // xor-swizzled fp32
    __shared__ __align__(16) float Vs[64][68];
    __shared__ __align__(16) float Ps[64][68];

    const int tid = threadIdx.x;
    const int tx = tid & 15, ty = tid >> 4;
    const int qt = (int)gridDim.x - 1 - (int)blockIdx.x;  // heavy blocks first
    const int h = blockIdx.y, b = blockIdx.z;

    const size_t bh = ((size_t)b * NHEADS + h) * SEQ * DK;
    const unsigned short* Qb = Q + bh;
    const unsigned short* Kb = K + bh;
    const unsigned short* Vb = V + bh;

    {   // stage Q tile (keep bf16)
        int r = tid >> 2, c0 = (tid & 3) << 4;
        const unsigned short* src = Qb + (qt * 64 + r) * DK + c0;
#pragma unroll
        for (int u = 0; u < 16; u += 4)
            *(ushort4*)&Qsh[r][c0 + u] = *(const ushort4*)(src + u);
    }

    float Oacc[4][4] = {};
    float m_run[4], l_run[4];
#pragma unroll
    for (int i = 0; i < 4; ++i) { m_run[i] = -__builtin_inff(); l_run[i] = 0.f; }

    for (int kt = 0; kt <= qt; ++kt) {
        __syncthreads();   // protect Ks/Vs/Ps reuse
        {   // stage K (swizzled), V tiles, bf16->fp32
            int r = tid >> 2, c0 = (tid & 3) << 4;
            const unsigned short* ks = Kb + (kt * 64 + r) * DK + c0;
            const unsigned short* vs = Vb + (kt * 64 + r) * DK + c0;
            int swz = (r >> 2) & 15;
#pragma unroll
            for (int u = 0; u < 16; u += 4) {
                ushort4 ku = *(const ushort4*)(ks + u);
                ushort4 vu = *(const ushort4*)(vs + u);
                int c = c0 + u;
                int pb = (((c >> 2) ^ swz) << 2);
                Ks[r * 64 + pb]     = bf2f(ku.x);
                Ks[r * 64 + pb + 1] = bf2f(ku.y);
                Ks[r * 64 + pb + 2] = bf2f(ku.z);
                Ks[r * 64 + pb + 3] = bf2f(ku.w);
                Vs[r][c]     = bf2f(vu.x);
                Vs[r][c + 1] = bf2f(vu.y);
                Vs[r][c + 2] = bf2f(vu.z);
                Vs[r][c + 3] = bf2f(vu.w);
            }
        }
        __syncthreads();

        // scores s[i][j] = q_row(ty*4+i) . k_row(tx*4+j)  (Q pre-scaled)
        float s[4][4] = {};
#pragma unroll
        for (int kd = 0; kd < 64; kd += 4) {
            float4 qv[4], kv[4];
#pragma unroll
            for (int i = 0; i < 4; ++i) {
                ushort4 qu = *(const ushort4*)&Qsh[ty * 4 + i][kd];
                qv[i].x = bf2f(qu.x); qv[i].y = bf2f(qu.y);
                qv[i].z = bf2f(qu.z); qv[i].w = bf2f(qu.w);
            }
#pragma unroll
            for (int j = 0; j < 4; ++j) {
                int kr = tx * 4 + j;
                int pb = (((kd >> 2) ^ ((kr >> 2) & 15)) << 2);
                kv[j] = *(const float4*)&Ks[kr * 64 + pb];
            }
#pragma unroll
            for (int i = 0; i < 4; ++i)
#pragma unroll
                for (int j = 0; j < 4; ++j)
                    s[i][j] += qv[i].x * kv[j].x + qv[i].y * kv[j].y +
                               qv[i].z * kv[j].z + qv[i].w * kv[j].w;
        }

        // online softmax (row reductions over the 16 tx lanes of this wave)
        float aph[4];
#pragma unroll
        for (int i = 0; i < 4; ++i) {
            int qg = qt * 64 + ty * 4 + i;
#pragma unroll
            for (int j = 0; j < 4; ++j) {
                int kg = kt * 64 + tx * 4 + j;
                if (kg > qg) s[i][j] = -__builtin_inff();
            }
            float mx = fmaxf(fmaxf(s[i][0], s[i][1]), fmaxf(s[i][2], s[i][3]));
            mx = fmaxf(mx, __shfl_xor(mx, 1));
            mx = fmaxf(mx, __shfl_xor(mx, 2));
            mx = fmaxf(mx, __shfl_xor(mx, 4));
            mx = fmaxf(mx, __shfl_xor(mx, 8));
            float mnew = fmaxf(m_run[i], mx);
            float alpha = __expf(m_run[i] - mnew);
            m_run[i] = mnew;
            float4 p;
            p.x = __expf(s[i][0] - mnew);
            p.y = __expf(s[i][1] - mnew);
            p.z = __expf(s[i][2] - mnew);
            p.w = __expf(s[i][3] - mnew);
            float rs = p.x + p.y + p.z + p.w;
            rs += __shfl_xor(rs, 1);
            rs += __shfl_xor(rs, 2);
            rs += __shfl_xor(rs, 4);
            rs += __shfl_xor(rs, 8);
            l_run[i] = l_run[i] * alpha + rs;
            aph[i] = alpha;
            *(float4*)&Ps[ty * 4 + i][tx * 4] = p;
        }
        __syncthreads();

        // O = O*alpha + P.V
#pragma unroll
        for (int i = 0; i < 4; ++i) {
            int q = ty * 4 + i;
            float al = aph[i];
            float o0 = Oacc[i][0] * al, o1 = Oacc[i][1] * al;
            float o2 = Oacc[i][2] * al, o3 = Oacc[i][3] * al;
            for (int kk = 0; kk < 64; kk += 4) {
                float4 p  = *(const float4*)&Ps[q][kk];
                float4 va = *(const float4*)&Vs[kk][tx * 4];
                float4 vb = *(const float4*)&Vs[kk + 1][tx * 4];
                float4 vc = *(const float4*)&Vs[kk + 2][tx * 4];
                float4 vd = *(const float4*)&Vs[kk + 3][tx * 4];
                o0 += p.x * va.x + p.y * vb.x + p.z * vc.x + p.w * vd.x;
                o1 += p.x * va.y + p.y * vb.y + p.z * vc.y + p.w * vd.y;
                o2 += p.x * va.z + p.y * vb.z + p.z * vc.z + p.w * vd.z;
                o3 += p.x * va.w + p.y * vb.w + p.z * vc.w + p.w * vd.w;
            }
            Oacc[i][0] = o0; Oacc[i][1] = o1; Oacc[i][2] = o2; Oacc[i][3] = o3;
        }
    }

    // write (B,S,H*Dk) bf16
#pragma unroll
    for (int i = 0; i < 4; ++i) {
        int qg = qt * 64 + ty * 4 + i;
        float inv = 1.f / l_run[i];
        ushort4 o;
        o.x = f2bf(Oacc[i][0] * inv);
        o.y = f2bf(Oacc[i][1] * inv);
        o.z = f2bf(Oacc[i][2] * inv);
        o.w = f2bf(Oacc[i][3] * inv);
        *(ushort4*)(O + ((size_t)(b * SEQ + qg)) * D_MODEL + h * DK + tx * 4) = o;
    }
}

// ---------------- launch ----------------

extern "C" void kernel_launch(void* const* d_in, const int* in_sizes, int n_in,
                              void* d_out, int out_size, void* d_ws, size_t ws_size,
                              hipStream_t stream) {
    const float* x  = (const float*)d_in[0];
    const float* wq = (const float*)d_in[1];
    const float* bq = (const float*)d_in[2];
    const float* wk = (const float*)d_in[3];
    const float* bk = (const float*)d_in[4];
    const float* wv = (const float*)d_in[5];
    const float* bv = (const float*)d_in[6];
    const float* wo = (const float*)d_in[7];
    const float* bo = (const float*)d_in[8];
    float* out = (float*)d_out;

    char* ws = (char*)d_ws;
    const size_t MB = 1u << 20;
    unsigned short* xb  = (unsigned short*)(ws);             // 16 MB  x bf16
    unsigned short* wqt = (unsigned short*)(ws + 16 * MB);   //  2 MB each
    unsigned short* wkt = (unsigned short*)(ws + 18 * MB);
    unsigned short* wvt = (unsigned short*)(ws + 20 * MB);
    unsigned short* wot = (unsigned short*)(ws + 22 * MB);
    unsigned short* qb  = (unsigned short*)(ws + 24 * MB);   // 16 MB each
    unsigned short* kb  = (unsigned short*)(ws + 40 * MB);
    unsigned short* vb  = (unsigned short*)(ws + 56 * MB);
    unsigned short* ab  = (unsigned short*)(ws + 72 * MB);   // attn out, ends 88 MB

    f32_to_bf16_k<<<(MROWS * D_MODEL / 4 + 255) / 256, 256, 0, stream>>>(
        x, xb, MROWS * D_MODEL / 4);
    dim3 tg(32, 32);
    transpose_to_bf16_k<<<tg, 256, 0, stream>>>(wq, wqt);
    transpose_to_bf16_k<<<tg, 256, 0, stream>>>(wk, wkt);
    transpose_to_bf16_k<<<tg, 256, 0, stream>>>(wv, wvt);
    transpose_to_bf16_k<<<tg, 256, 0, stream>>>(wo, wot);

    dim3 gg(D_MODEL / 128, MROWS / 128);
    gemm_bf16<<<gg, 256, 0, stream>>>(xb, wqt, bq, qb, 0.125f, 0);  // Q (pre-scaled 1/sqrt(Dk))
    gemm_bf16<<<gg, 256, 0, stream>>>(xb, wkt, bk, kb, 1.0f, 0);    // K
    gemm_bf16<<<gg, 256, 0, stream>>>(xb, wvt, bv, vb, 1.0f, 0);    // V

    attn_fp32<<<dim3(SEQ / 64, NHEADS, BATCH), 256, 0, stream>>>(qb, kb, vb, ab);

    gemm_bf16<<<gg, 256, 0, stream>>>(ab, wot, bo, out, 1.0f, 1);   // out proj
}

// Round 2
// 611.680 us; speedup vs baseline: 11.2503x; 11.2503x over previous
//
#include <hip/hip_runtime.h>
#include <hip/hip_bf16.h>

// MultiHeadSelfAttention on MI355X (gfx950)
// Pipeline: [f32->bf16 x] [transpose W* -> bf16 N-major] -> 3x MFMA GEMM (QKV,
// scattered to (B,H,S,Dk), Q pre-scaled by log2e/sqrt(Dk)) -> MFMA flash
// attention (bf16 in, fp32 accum, exp2-domain online softmax) ->
// MFMA GEMM out-proj (fp32 out + bias).

#define D_MODEL 1024
#define NHEADS  16
#define DK      64
#define BATCH   4
#define SEQ     2048
#define MROWS   (BATCH*SEQ)   // 8192

typedef short bvec8 __attribute__((ext_vector_type(8)));   // 8 bf16 = 4 VGPRs (MFMA A/B frag)
typedef float fvec4 __attribute__((ext_vector_type(4)));   // MFMA C/D frag

__device__ __forceinline__ unsigned short f2bf(float f) {
    unsigned int x = __float_as_uint(f);
    x += 0x7fffu + ((x >> 16) & 1u);   // RNE
    return (unsigned short)(x >> 16);
}
__device__ __forceinline__ float bf2f(unsigned short u) {
    return __uint_as_float(((unsigned int)u) << 16);
}

// ---------------- prep kernels ----------------

__global__ void f32_to_bf16_k(const float* __restrict__ in,
                              unsigned short* __restrict__ out, int n4) {
    int i = blockIdx.x * 256 + threadIdx.x;
    if (i < n4) {
        float4 v = ((const float4*)in)[i];
        ushort4 o;
        o.x = f2bf(v.x); o.y = f2bf(v.y); o.z = f2bf(v.z); o.w = f2bf(v.w);
        ((ushort4*)out)[i] = o;
    }
}

// Wt[n][k] = (bf16) W[k][n]   (1024x1024)
__global__ void transpose_to_bf16_k(const float* __restrict__ W,
                                    unsigned short* __restrict__ Wt) {
    __shared__ float tile[32][33];
    int n0 = blockIdx.x * 32, k0 = blockIdx.y * 32;
    int tx = threadIdx.x & 31;
    int ty = (threadIdx.x >> 5) * 4;
#pragma unroll
    for (int i = 0; i < 4; ++i)
        tile[ty + i][tx] = W[(k0 + ty + i) * D_MODEL + n0 + tx];
    __syncthreads();
#pragma unroll
    for (int i = 0; i < 4; ++i)
        Wt[(n0 + ty + i) * D_MODEL + k0 + tx] = f2bf(tile[tx][ty + i]);
}

// ---------------- bf16 MFMA GEMM ----------------
// C(128x128/block) = A(M x 1024, bf16 row-major) * Bt^T (Bt is N x K bf16) + bias
// mode 0: store bf16 scattered to (b,h,s,d) with pre-store scale
// mode 1: store fp32 row-major (d_out)
__global__ __launch_bounds__(256, 2)
void gemm_bf16(const unsigned short* __restrict__ A,
               const unsigned short* __restrict__ Bt,
               const float* __restrict__ bias,
               void* __restrict__ Out, float scale, int mode) {
    __shared__ unsigned short As[128][72];   // +8 bf16 pad, 16B-aligned rows
    __shared__ unsigned short Bs[128][72];

    const int tid  = threadIdx.x;
    const int lane = tid & 63;
    const int w    = tid >> 6;
    const int wr   = w >> 1, wc = w & 1;     // 2x2 waves, 64x64 each
    const int quad = lane >> 4, l16 = lane & 15;
    const int rowBlock = blockIdx.y * 128;
    const int colBlock = blockIdx.x * 128;

    fvec4 acc[4][4] = {};

    for (int k0 = 0; k0 < D_MODEL; k0 += 64) {
#pragma unroll
        for (int it = 0; it < 4; ++it) {
            int c  = tid + it * 256;          // 1024 chunks of 8 bf16
            int r  = c >> 3;
            int cc = (c & 7) << 3;
            *(bvec8*)&As[r][cc] = *(const bvec8*)&A[(rowBlock + r) * D_MODEL + k0 + cc];
            *(bvec8*)&Bs[r][cc] = *(const bvec8*)&Bt[(colBlock + r) * D_MODEL + k0 + cc];
        }
        __syncthreads();
#pragma unroll
        for (int kk = 0; kk < 64; kk += 32) {
            bvec8 af[4], bfr[4];
#pragma unroll
            for (int i = 0; i < 4; ++i)
                af[i] = *(const bvec8*)&As[wr * 64 + i * 16 + l16][kk + quad * 8];
#pragma unroll
            for (int j = 0; j < 4; ++j)
                bfr[j] = *(const bvec8*)&Bs[wc * 64 + j * 16 + l16][kk + quad * 8];
#pragma unroll
            for (int i = 0; i < 4; ++i)
#pragma unroll
                for (int j = 0; j < 4; ++j)
                    acc[i][j] = __builtin_amdgcn_mfma_f32_16x16x32_bf16(
                        af[i], bfr[j], acc[i][j], 0, 0, 0);
        }
        __syncthreads();
    }

    // epilogue: D[row=quad*4+r][col=l16] per 16x16 tile (m89-verified mapping)
    if (mode == 0) {
        unsigned short* Oq = (unsigned short*)Out;
#pragma unroll
        for (int i = 0; i < 4; ++i) {
#pragma unroll
            for (int j = 0; j < 4; ++j) {
                int ncol = colBlock + wc * 64 + j * 16 + l16;
                float bv = bias[ncol];
                int h = ncol >> 6, d = ncol & 63;
#pragma unroll
                for (int r = 0; r < 4; ++r) {
                    int mrow = rowBlock + wr * 64 + i * 16 + quad * 4 + r;
                    int b = mrow >> 11, s = mrow & (SEQ - 1);
                    float v = (acc[i][j][r] + bv) * scale;
                    Oq[(((b * NHEADS + h) * SEQ + s) * DK) + d] = f2bf(v);
                }
            }
        }
    } else {
        float* Of = (float*)Out;
#pragma unroll
        for (int i = 0; i < 4; ++i) {
#pragma unroll
            for (int j = 0; j < 4; ++j) {
                int ncol = colBlock + wc * 64 + j * 16 + l16;
                float bv = bias[ncol];
#pragma unroll
                for (int r = 0; r < 4; ++r) {
                    int mrow = rowBlock + wr * 64 + i * 16 + quad * 4 + r;
                    Of[mrow * D_MODEL + ncol] = acc[i][j][r] + bv;
                }
            }
        }
    }
}

// ---------------- MFMA flash attention ----------------
// grid (32,16,4): one block per (q-tile of 64, head, batch), 256 thr = 4 waves.
// Wave wq owns q rows [wq*16, wq*16+16). Per K/V tile of 64:
//   S = Q.K^T via 8 MFMAs -> online softmax in C-layout registers
//   P -> wave-private LDS rows (bf16) -> A-frags; V staged transposed -> B-frags
//   O += P.V via 8 MFMAs. m/l/alpha per (quad, r) need no cross-lane beyond
//   the 16-lane shfl_xor row reductions (S and O share the C-layout row map).
__global__ __launch_bounds__(256, 4)
void attn_mfma(const unsigned short* __restrict__ Q,   // (B,H,S,Dk) bf16, pre-scaled log2e/8
               const unsigned short* __restrict__ K,
               const unsigned short* __restrict__ V,
               unsigned short* __restrict__ O) {       // (B,S,H*Dk) bf16
    __shared__ __align__(16) unsigned short Qs[64][72];
    __shared__ __align__(16) unsigned short Ks[64][72];
    __shared__ __align__(16) unsigned short Vt[64][72];  // [d][key]
    __shared__ __align__(16) unsigned short Pl[64][72];  // wave-private 16-row bands

    const int tid  = threadIdx.x;
    const int lane = tid & 63;
    const int wq   = tid >> 6;               // wave id -> q-row band
    const int quad = lane >> 4, l16 = lane & 15;
    const int qt = (int)gridDim.x - 1 - (int)blockIdx.x;  // heavy blocks first
    const int h = blockIdx.y, b = blockIdx.z;

    const size_t bh = ((size_t)b * NHEADS + h) * SEQ * DK;
    const unsigned short* Qb = Q + bh;
    const unsigned short* Kb = K + bh;
    const unsigned short* Vb = V + bh;

    const int sr = tid >> 2;                 // staging row 0..63
    const int sc = (tid & 3) << 4;           // staging col {0,16,32,48}

    {   // stage Q tile (row-major bf16)
        const unsigned short* src = Qb + (qt * 64 + sr) * DK + sc;
        *(bvec8*)&Qs[sr][sc]     = *(const bvec8*)src;
        *(bvec8*)&Qs[sr][sc + 8] = *(const bvec8*)(src + 8);
    }

    fvec4 acc_o[4] = {};   // [jd]: O[q=quad*4+r][d=jd*16+l16]
    float m_run[4], l_run[4];
#pragma unroll
    for (int r = 0; r < 4; ++r) { m_run[r] = -__builtin_inff(); l_run[r] = 0.f; }

    for (int kt = 0; kt <= qt; ++kt) {
        __syncthreads();   // prior tile's LDS reads done (also covers Q staging)
        {   // stage K row-major + V transposed
            const unsigned short* ks = Kb + (kt * 64 + sr) * DK + sc;
            bvec8 k0 = *(const bvec8*)ks;
            bvec8 k1 = *(const bvec8*)(ks + 8);
            const unsigned short* vs = Vb + (kt * 64 + sr) * DK + sc;
            bvec8 v0 = *(const bvec8*)vs;
            bvec8 v1 = *(const bvec8*)(vs + 8);
            *(bvec8*)&Ks[sr][sc]     = k0;
            *(bvec8*)&Ks[sr][sc + 8] = k1;
#pragma unroll
            for (int u = 0; u < 8; ++u) {
                Vt[sc + u][sr]     = v0[u];
                Vt[sc + 8 + u][sr] = v1[u];
            }
        }
        __syncthreads();

        // S(16q x 64k) = Q . K^T
        fvec4 s[4] = {};
#pragma unroll
        for (int kc = 0; kc < 2; ++kc) {
            bvec8 aq = *(const bvec8*)&Qs[wq * 16 + l16][kc * 32 + quad * 8];
#pragma unroll
            for (int j = 0; j < 4; ++j) {
                bvec8 bk = *(const bvec8*)&Ks[j * 16 + l16][kc * 32 + quad * 8];
                s[j] = __builtin_amdgcn_mfma_f32_16x16x32_bf16(aq, bk, s[j], 0, 0, 0);
            }
        }

        if (kt == qt) {   // causal mask (diagonal tile only)
#pragma unroll
            for (int j = 0; j < 4; ++j)
#pragma unroll
                for (int r = 0; r < 4; ++r) {
                    int kl = j * 16 + l16, ql = wq * 16 + quad * 4 + r;
                    if (kl > ql) s[j][r] = -__builtin_inff();
                }
        }

        // online softmax in exp2 domain (scores pre-scaled by log2e/sqrt(Dk))
        float alpha[4];
#pragma unroll
        for (int r = 0; r < 4; ++r) {
            float mx = fmaxf(fmaxf(s[0][r], s[1][r]), fmaxf(s[2][r], s[3][r]));
            mx = fmaxf(mx, __shfl_xor(mx, 1));
            mx = fmaxf(mx, __shfl_xor(mx, 2));
            mx = fmaxf(mx, __shfl_xor(mx, 4));
            mx = fmaxf(mx, __shfl_xor(mx, 8));
            float mnew = fmaxf(m_run[r], mx);
            alpha[r] = exp2f(m_run[r] - mnew);
            m_run[r] = mnew;
            float rs = 0.f;
#pragma unroll
            for (int j = 0; j < 4; ++j) {
                float p = exp2f(s[j][r] - mnew);
                s[j][r] = p;
                rs += p;
            }
            rs += __shfl_xor(rs, 1);
            rs += __shfl_xor(rs, 2);
            rs += __shfl_xor(rs, 4);
            rs += __shfl_xor(rs, 8);
            l_run[r] = l_run[r] * alpha[r] + rs;
        }

        // P (C-layout) -> wave-private LDS rows (A-layout source for PV)
#pragma unroll
        for (int j = 0; j < 4; ++j)
#pragma unroll
            for (int r = 0; r < 4; ++r)
                Pl[wq * 16 + quad * 4 + r][j * 16 + l16] = f2bf(s[j][r]);

        // O = O*alpha + P.V   (same-wave LDS dependency; compiler emits lgkmcnt)
#pragma unroll
        for (int jd = 0; jd < 4; ++jd)
#pragma unroll
            for (int r = 0; r < 4; ++r)
                acc_o[jd][r] *= alpha[r];
#pragma unroll
        for (int kc = 0; kc < 2; ++kc) {
            bvec8 ap = *(const bvec8*)&Pl[wq * 16 + l16][kc * 32 + quad * 8];
#pragma unroll
            for (int jd = 0; jd < 4; ++jd) {
                bvec8 bv = *(const bvec8*)&Vt[jd * 16 + l16][kc * 32 + quad * 8];
                acc_o[jd] = __builtin_amdgcn_mfma_f32_16x16x32_bf16(ap, bv, acc_o[jd], 0, 0, 0);
            }
        }
    }

    // write O tile: (B,S,H*Dk) bf16
#pragma unroll
    for (int r = 0; r < 4; ++r) {
        int qg = qt * 64 + wq * 16 + quad * 4 + r;
        float inv = 1.f / l_run[r];
        unsigned short* dst = O + ((size_t)(b * SEQ + qg)) * D_MODEL + h * DK;
#pragma unroll
        for (int jd = 0; jd < 4; ++jd)
            dst[jd * 16 + l16] = f2bf(acc_o[jd][r] * inv);
    }
}

// ---------------- launch ----------------

extern "C" void kernel_launch(void* const* d_in, const int* in_sizes, int n_in,
                              void* d_out, int out_size, void* d_ws, size_t ws_size,
                              hipStream_t stream) {
    const float* x  = (const float*)d_in[0];
    const float* wq = (const float*)d_in[1];
    const float* bq = (const float*)d_in[2];
    const float* wk = (const float*)d_in[3];
    const float* bk = (const float*)d_in[4];
    const float* wv = (const float*)d_in[5];
    const float* bv = (const float*)d_in[6];
    const float* wo = (const float*)d_in[7];
    const float* bo = (const float*)d_in[8];
    float* out = (float*)d_out;

    char* ws = (char*)d_ws;
    const size_t MB = 1u << 20;
    unsigned short* xb  = (unsigned short*)(ws);             // 16 MB  x bf16
    unsigned short* wqt = (unsigned short*)(ws + 16 * MB);   //  2 MB each
    unsigned short* wkt = (unsigned short*)(ws + 18 * MB);
    unsigned short* wvt = (unsigned short*)(ws + 20 * MB);
    unsigned short* wot = (unsigned short*)(ws + 22 * MB);
    unsigned short* qb  = (unsigned short*)(ws + 24 * MB);   // 16 MB each
    unsigned short* kb  = (unsigned short*)(ws + 40 * MB);
    unsigned short* vb  = (unsigned short*)(ws + 56 * MB);
    unsigned short* ab  = (unsigned short*)(ws + 72 * MB);   // attn out, ends 88 MB

    f32_to_bf16_k<<<(MROWS * D_MODEL / 4 + 255) / 256, 256, 0, stream>>>(
        x, xb, MROWS * D_MODEL / 4);
    dim3 tg(32, 32);
    transpose_to_bf16_k<<<tg, 256, 0, stream>>>(wq, wqt);
    transpose_to_bf16_k<<<tg, 256, 0, stream>>>(wk, wkt);
    transpose_to_bf16_k<<<tg, 256, 0, stream>>>(wv, wvt);
    transpose_to_bf16_k<<<tg, 256, 0, stream>>>(wo, wot);

    // Q pre-scale folds softmax's 1/sqrt(Dk) AND log2(e) for exp2-domain softmax
    const float QSCALE = 0.125f * 1.44269504088896340736f;

    dim3 gg(D_MODEL / 128, MROWS / 128);
    gemm_bf16<<<gg, 256, 0, stream>>>(xb, wqt, bq, qb, QSCALE, 0);  // Q
    gemm_bf16<<<gg, 256, 0, stream>>>(xb, wkt, bk, kb, 1.0f, 0);    // K
    gemm_bf16<<<gg, 256, 0, stream>>>(xb, wvt, bv, vb, 1.0f, 0);    // V

    attn_mfma<<<dim3(SEQ / 64, NHEADS, BATCH), 256, 0, stream>>>(qb, kb, vb, ab);

    gemm_bf16<<<gg, 256, 0, stream>>>(ab, wot, bo, out, 1.0f, 1);   // out proj
}